// Round 7
// baseline (158.804 us; speedup 1.0000x reference)
//
#include <hip/hip_runtime.h>

#define NR 131072
#define DD 32
#define KK 64
#define BETA_C 10.0f
#define WROWS 256                    // rows per syrk worker
#define GRIDW 640                    // >= sum ceil(c_k/WROWS) <= 512+64 = 576
#define TRI(i, j) ((i) * ((i) + 1) / 2 + (j))

// ---------------------------------------------------------------------------
// ws layout (float-indexed), ws_size = 256 MiB (R6 counter evidence):
//   [0,64)        fill_g    [64,65) lossAcc
//   [128,192)     hist_g (int)      [192,260) segStart (int 65)
//   [320,384)     cursor (int)      [384,544) wk (uchar GRIDW)
//   [544,1184)    wbase (int)       [1184,1824) wcnt (int)
//   [1824,35616)  m2low_g (K x 528 tri)   [35616,37664) sums_g (K x 32)
//   [37664,70432) pred8 (uchar N)   [70432,+N*D) xsort (cluster-sorted x)
// memset zeroes [0,37664) floats; everything past is fully overwritten.
// ---------------------------------------------------------------------------

// phase 1 (R6 verbatim, validated): one row/thread, centers via wave-uniform
// s_load path, 63-shuffle transpose-reduce for filling, per-block histogram.
__global__ __launch_bounds__(256) void phase1_kernel(
    const float* __restrict__ x, const float* __restrict__ centers,
    float* __restrict__ fill_g, int* __restrict__ hist_g,
    unsigned char* __restrict__ pred_g) {
  __shared__ float cnS[KK];
  __shared__ float fillW[4][KK];
  __shared__ int histS[KK];

  const int tid = threadIdx.x;
  const int lane = tid & 63;
  const int wid = tid >> 6;

  if (tid < KK) {
    float s = 0.f;
    const float* cp = centers + tid * DD;
#pragma unroll
    for (int j = 0; j < DD; ++j) s += cp[j] * cp[j];
    cnS[tid] = s;
    histS[tid] = 0;
  }
  __syncthreads();

  const int row = blockIdx.x * 256 + tid;  // grid == NR/256 exactly

  float xr[DD];
  const float4* xp = (const float4*)(x + (size_t)row * DD);
#pragma unroll
  for (int j = 0; j < 8; ++j) {
    const float4 v = xp[j];
    xr[4 * j + 0] = v.x;
    xr[4 * j + 1] = v.y;
    xr[4 * j + 2] = v.z;
    xr[4 * j + 3] = v.w;
  }
  float xx = 0.f;
#pragma unroll
  for (int j = 0; j < DD; ++j) xx += xr[j] * xr[j];

  float pv[KK];
  float best = 3.4e38f;
  int bi = 0;
#pragma unroll
  for (int k = 0; k < KK; ++k) {
    float dot = 0.f;
#pragma unroll
    for (int j = 0; j < DD; ++j)
      dot += xr[j] * centers[k * DD + j];  // uniform addr -> s_load (K$)
    const float d2 = xx - 2.0f * dot + cnS[k];
    pv[k] = d2;
    if (d2 < best) { best = d2; bi = k; }  // strict < == first-index ties
  }
  pred_g[row] = (unsigned char)bi;
  atomicAdd(&histS[bi], 1);

  float ssum = 0.f;
#pragma unroll
  for (int k = 0; k < KK; ++k) {
    const float e = __expf(BETA_C * (best - pv[k]));
    pv[k] = e;
    ssum += e;
  }
  const float inv = 1.0f / ssum;
#pragma unroll
  for (int k = 0; k < KK; ++k) pv[k] *= inv;

#pragma unroll
  for (int m = 32; m >= 1; m >>= 1) {
    const bool hi = (lane & m) != 0;
#pragma unroll
    for (int i = 0; i < m; ++i) {
      const float send = hi ? pv[i] : pv[i + m];
      const float recv = __shfl_xor(send, m, 64);
      const float keep = hi ? pv[i + m] : pv[i];
      pv[i] = keep + recv;
    }
  }
  fillW[wid][lane] = pv[0];
  __syncthreads();
  if (tid < KK) {
    atomicAdd(&fill_g[tid],
              fillW[0][tid] + fillW[1][tid] + fillW[2][tid] + fillW[3][tid]);
    if (histS[tid]) atomicAdd(&hist_g[tid], histS[tid]);
  }
}

// planner: prefix hist -> segment starts, init cursors, emit worker table
// (each worker: cluster k + a WROWS-slice of k's segment). 255 = idle.
__global__ void planner_kernel(const int* __restrict__ hist_g,
                               int* __restrict__ segStart,
                               int* __restrict__ cursor,
                               unsigned char* __restrict__ wk,
                               int* __restrict__ wbase,
                               int* __restrict__ wcnt) {
  if (threadIdx.x != 0) return;
  int acc = 0;
  int seg[KK + 1];
  for (int k = 0; k < KK; ++k) {
    seg[k] = acc;
    acc += hist_g[k];
  }
  seg[KK] = acc;  // == NR
  for (int k = 0; k <= KK; ++k) segStart[k] = seg[k];
  for (int k = 0; k < KK; ++k) cursor[k] = seg[k];
  int w = 0;
  for (int k = 0; k < KK; ++k) {
    const int c = hist_g[k];
    for (int wi = 0; wi * WROWS < c; ++wi) {
      wk[w] = (unsigned char)k;
      wbase[w] = seg[k] + wi * WROWS;
      wcnt[w] = min(WROWS, c - wi * WROWS);
      ++w;
    }
  }
  for (; w < GRIDW; ++w) wk[w] = 255;
}

// scatter: counting-sort x into xsort (cluster-contiguous). Per block: LDS
// rank (block hist + one global cursor claim per (block,cluster)), then a
// fully-coalesced float4 copy (8 consecutive threads move one 128B row).
__global__ __launch_bounds__(256) void scatter_kernel(
    const float* __restrict__ x, const unsigned char* __restrict__ pred_g,
    int* __restrict__ cursor, float* __restrict__ xsort) {
  __shared__ int histS[KK];
  __shared__ int baseS[KK];
  __shared__ int slotS[256];

  const int tid = threadIdx.x;
  if (tid < KK) histS[tid] = 0;
  __syncthreads();

  const int row = blockIdx.x * 256 + tid;
  const int bi = pred_g[row];
  const int rank = atomicAdd(&histS[bi], 1);
  __syncthreads();
  if (tid < KK) {
    const int h = histS[tid];
    baseS[tid] = h ? atomicAdd(&cursor[tid], h) : 0;
  }
  __syncthreads();
  slotS[tid] = baseS[bi] + rank;
  __syncthreads();

  const float4* xin = (const float4*)x + (size_t)blockIdx.x * 2048;
  float4* xo = (float4*)xsort;
#pragma unroll
  for (int j = 0; j < 8; ++j) {
    const int f = tid + 256 * j;     // float4 index within the 256-row slab
    const int rl = f >> 3;           // local row
    const int pt = f & 7;            // float4 within row
    xo[(size_t)slotS[rl] * 8 + pt] = xin[f];  // reads perfectly coalesced
  }
}

// syrk v3: worker = (cluster k, <=256 contiguous sorted rows). Coalesced
// gather into the R6-validated transposed LDS tile; 2x2 register-tile
// accumulation; R6-validated lower-triangle flush (576 blocks -> 4.5x fewer
// atomics than R6).
__global__ __launch_bounds__(256) void syrk_kernel(
    const float* __restrict__ xsort, const unsigned char* __restrict__ wk,
    const int* __restrict__ wbase, const int* __restrict__ wcnt,
    float* __restrict__ m2low_g, float* __restrict__ sums_g) {
  __shared__ float xsT[DD][68];  // transposed tile, 8.7 KB

  const int b = blockIdx.x;
  const int k = wk[b];
  if (k == 255) return;
  const int tid = threadIdx.x;
  const int base = wbase[b];
  const int total = wcnt[b];

  const int ti = tid >> 4, tj = tid & 15;
  const int i0 = ti, i1 = ti + 16, j0 = tj, j1 = tj + 16;
  float c00 = 0.f, c10 = 0.f, c11 = 0.f, sd0 = 0.f, sd1 = 0.f;

  for (int off = 0; off < total; off += 64) {
    const int cnt = min(64, total - off);
    const int cnt4 = (cnt + 3) & ~3;
    __syncthreads();  // previous tile's readers done before overwrite
    const float* src = xsort + (size_t)(base + off) * DD;
    for (int e = tid; e < cnt * DD; e += 256)
      xsT[e & 31][e >> 5] = src[e];  // fully coalesced
    for (int e = cnt * DD + tid; e < cnt4 * DD; e += 256)
      xsT[e & 31][e >> 5] = 0.f;  // zero-pad rows to multiple of 4
    __syncthreads();
    for (int g = 0; g < (cnt4 >> 2); ++g) {
      const float4 A0 = *(const float4*)&xsT[i0][4 * g];
      const float4 A1 = *(const float4*)&xsT[i1][4 * g];
      const float4 B0 = *(const float4*)&xsT[j0][4 * g];
      const float4 B1 = *(const float4*)&xsT[j1][4 * g];
      c00 += A0.x * B0.x + A0.y * B0.y + A0.z * B0.z + A0.w * B0.w;
      c10 += A1.x * B0.x + A1.y * B0.y + A1.z * B0.z + A1.w * B0.w;
      c11 += A1.x * B1.x + A1.y * B1.y + A1.z * B1.z + A1.w * B1.w;
      if (tj == 0) {  // sums from already-loaded registers
        sd0 += A0.x + A0.y + A0.z + A0.w;
        sd1 += A1.x + A1.y + A1.z + A1.w;
      }
    }
  }

  float* m2k = m2low_g + k * 528;
  atomicAdd(&m2k[TRI(i1, j0)], c10);
  if (tj <= ti) {
    atomicAdd(&m2k[TRI(i0, j0)], c00);
    atomicAdd(&m2k[TRI(i1, j1)], c11);
  }
  if (tj == 0) {
    atomicAdd(&sums_g[k * DD + i0], sd0);
    atomicAdd(&sums_g[k * DD + i1], sd1);
  }
}

// finalize A (R6 verbatim, validated): one block per cluster.
__global__ __launch_bounds__(256) void finalizeA_kernel(
    const float* __restrict__ fill_g, const int* __restrict__ hist_g,
    const float* __restrict__ sums_g, const float* __restrict__ m2low_g,
    const float* __restrict__ ft, const float* __restrict__ mt,
    const float* __restrict__ ct, float* __restrict__ lossAcc) {
  __shared__ float meanS[DD];
  __shared__ float wred[4];
  const int t = threadIdx.x;
  const int k = blockIdx.x;

  const float inv = 1.0f / fmaxf((float)hist_g[k], 1.0f);
  if (t < DD) meanS[t] = sums_g[k * DD + t] * inv;
  __syncthreads();

  float acc = 0.f;
  if (t < DD) {
    const float d = meanS[t] - mt[k * DD + t];
    acc += d * d * (1.0f / (KK * DD));
  }
  if (t == 0) {
    const float f = fill_g[k] * (1.0f / (float)NR) - ft[k];
    acc += f * f * (1.0f / KK);
  }
  const float* m2k = m2low_g + k * 528;
  const float* ctk = ct + k * (DD * DD);
#pragma unroll
  for (int u = 0; u < 4; ++u) {
    const int e = t + 256 * u;
    const int i = e >> 5, j = e & 31;
    const int idx = (i >= j) ? TRI(i, j) : TRI(j, i);
    const float cov = m2k[idx] * inv - meanS[i] * meanS[j];
    const float d = cov - ctk[e];
    acc += d * d * (1.0f / (KK * DD * DD));
  }

  acc += __shfl_xor(acc, 32, 64);
  acc += __shfl_xor(acc, 16, 64);
  acc += __shfl_xor(acc, 8, 64);
  acc += __shfl_xor(acc, 4, 64);
  acc += __shfl_xor(acc, 2, 64);
  acc += __shfl_xor(acc, 1, 64);
  if ((t & 63) == 0) wred[t >> 6] = acc;
  __syncthreads();
  if (t == 0) atomicAdd(lossAcc, wred[0] + wred[1] + wred[2] + wred[3]);
}

__global__ void finalizeB_kernel(const float* __restrict__ lossAcc,
                                 float* __restrict__ out) {
  if (threadIdx.x == 0) out[0] = lossAcc[0];
}

extern "C" void kernel_launch(void* const* d_in, const int* in_sizes, int n_in,
                              void* d_out, int out_size, void* d_ws,
                              size_t ws_size, hipStream_t stream) {
  (void)in_sizes; (void)n_in; (void)out_size; (void)ws_size;
  const float* x = (const float*)d_in[0];
  const float* centers = (const float*)d_in[1];
  const float* ft = (const float*)d_in[2];
  const float* mt = (const float*)d_in[3];
  const float* ct = (const float*)d_in[4];
  float* out = (float*)d_out;

  float* ws = (float*)d_ws;
  float* fill_g = ws;                                   // 64
  float* lossAcc = ws + 64;                             // 1
  int* hist_g = (int*)(ws + 128);                       // 64
  int* segStart = (int*)(ws + 192);                     // 65
  int* cursor = (int*)(ws + 320);                       // 64
  unsigned char* wk = (unsigned char*)(ws + 384);       // GRIDW bytes
  int* wbase = (int*)(ws + 544);                        // GRIDW
  int* wcnt = (int*)(ws + 1184);                        // GRIDW
  float* m2low_g = ws + 1824;                           // 33792
  float* sums_g = ws + 35616;                           // 2048
  unsigned char* pred8 = (unsigned char*)(ws + 37664);  // N bytes
  float* xsort = ws + 70432;                            // N*D floats (16 MB)

  hipMemsetAsync(d_ws, 0, (size_t)37664 * sizeof(float), stream);

  phase1_kernel<<<NR / 256, 256, 0, stream>>>(x, centers, fill_g, hist_g,
                                              pred8);
  planner_kernel<<<1, 64, 0, stream>>>(hist_g, segStart, cursor, wk, wbase,
                                       wcnt);
  scatter_kernel<<<NR / 256, 256, 0, stream>>>(x, pred8, cursor, xsort);
  syrk_kernel<<<GRIDW, 256, 0, stream>>>(xsort, wk, wbase, wcnt, m2low_g,
                                         sums_g);
  finalizeA_kernel<<<KK, 256, 0, stream>>>(fill_g, hist_g, sums_g, m2low_g, ft,
                                           mt, ct, lossAcc);
  finalizeB_kernel<<<1, 64, 0, stream>>>(lossAcc, out);
}

// Round 8
// 135.782 us; speedup vs baseline: 1.1696x; 1.1696x over previous
//
#include <hip/hip_runtime.h>

#define NR 131072
#define DD 32
#define KK 64
#define BETA_C 10.0f
#define WROWS 256                    // rows per syrk worker
#define GRIDW 640                    // >= sum ceil(c_k/WROWS) <= 512+64 = 576
#define TRI(i, j) ((i) * ((i) + 1) / 2 + (j))

// ---------------------------------------------------------------------------
// ws layout (float-indexed), ws_size = 256 MiB (R6 counter evidence):
//   [0,64)        fill_g    [64,65) lossAcc
//   [128,192)     hist_g (int)      [192,260) segStart (int 65)
//   [320,384)     cursor (int)      [384,544) wk (uchar GRIDW)
//   [544,1184)    wbase (int)       [1184,1824) wcnt (int)
//   [1824,35616)  m2low_g (K x 528 tri)   [35616,37664) sums_g (K x 32)
//   [37664,70432) pred8 (uchar N)   [70432,+N*D) xsort (cluster-sorted x)
// memset zeroes [0,37664) floats; everything past is fully overwritten.
// ---------------------------------------------------------------------------

// phase 1 (R6 verbatim, validated): one row/thread, centers via wave-uniform
// s_load path, 63-shuffle transpose-reduce for filling, per-block histogram.
__global__ __launch_bounds__(256) void phase1_kernel(
    const float* __restrict__ x, const float* __restrict__ centers,
    float* __restrict__ fill_g, int* __restrict__ hist_g,
    unsigned char* __restrict__ pred_g) {
  __shared__ float cnS[KK];
  __shared__ float fillW[4][KK];
  __shared__ int histS[KK];

  const int tid = threadIdx.x;
  const int lane = tid & 63;
  const int wid = tid >> 6;

  if (tid < KK) {
    float s = 0.f;
    const float* cp = centers + tid * DD;
#pragma unroll
    for (int j = 0; j < DD; ++j) s += cp[j] * cp[j];
    cnS[tid] = s;
    histS[tid] = 0;
  }
  __syncthreads();

  const int row = blockIdx.x * 256 + tid;  // grid == NR/256 exactly

  float xr[DD];
  const float4* xp = (const float4*)(x + (size_t)row * DD);
#pragma unroll
  for (int j = 0; j < 8; ++j) {
    const float4 v = xp[j];
    xr[4 * j + 0] = v.x;
    xr[4 * j + 1] = v.y;
    xr[4 * j + 2] = v.z;
    xr[4 * j + 3] = v.w;
  }
  float xx = 0.f;
#pragma unroll
  for (int j = 0; j < DD; ++j) xx += xr[j] * xr[j];

  float pv[KK];
  float best = 3.4e38f;
  int bi = 0;
#pragma unroll
  for (int k = 0; k < KK; ++k) {
    float dot = 0.f;
#pragma unroll
    for (int j = 0; j < DD; ++j)
      dot += xr[j] * centers[k * DD + j];  // uniform addr -> s_load (K$)
    const float d2 = xx - 2.0f * dot + cnS[k];
    pv[k] = d2;
    if (d2 < best) { best = d2; bi = k; }  // strict < == first-index ties
  }
  pred_g[row] = (unsigned char)bi;
  atomicAdd(&histS[bi], 1);

  float ssum = 0.f;
#pragma unroll
  for (int k = 0; k < KK; ++k) {
    const float e = __expf(BETA_C * (best - pv[k]));
    pv[k] = e;
    ssum += e;
  }
  const float inv = 1.0f / ssum;
#pragma unroll
  for (int k = 0; k < KK; ++k) pv[k] *= inv;

#pragma unroll
  for (int m = 32; m >= 1; m >>= 1) {
    const bool hi = (lane & m) != 0;
#pragma unroll
    for (int i = 0; i < m; ++i) {
      const float send = hi ? pv[i] : pv[i + m];
      const float recv = __shfl_xor(send, m, 64);
      const float keep = hi ? pv[i + m] : pv[i];
      pv[i] = keep + recv;
    }
  }
  fillW[wid][lane] = pv[0];
  __syncthreads();
  if (tid < KK) {
    atomicAdd(&fill_g[tid],
              fillW[0][tid] + fillW[1][tid] + fillW[2][tid] + fillW[3][tid]);
    if (histS[tid]) atomicAdd(&hist_g[tid], histS[tid]);
  }
}

// planner v2 (parallel): 64 threads. Wave-shuffle exclusive scans replace the
// R7 single-thread serial loops (82.6 us, VALUBusy 0.002% -> launch-bound).
__global__ void planner_kernel(const int* __restrict__ hist_g,
                               int* __restrict__ segStart,
                               int* __restrict__ cursor,
                               unsigned char* __restrict__ wk,
                               int* __restrict__ wbase,
                               int* __restrict__ wcnt) {
  const int t = threadIdx.x;  // 64 threads, one wave
  const int c = hist_g[t];

  // inclusive scan of hist over the wave
  int inc = c;
#pragma unroll
  for (int off = 1; off < 64; off <<= 1) {
    const int v = __shfl_up(inc, off, 64);
    if (t >= off) inc += v;
  }
  const int seg = inc - c;  // exclusive
  segStart[t] = seg;
  cursor[t] = seg;
  if (t == 63) segStart[KK] = inc;  // == NR

  // scan of per-cluster worker counts -> worker-table offsets
  const int nw = (c + WROWS - 1) / WROWS;
  int winc = nw;
#pragma unroll
  for (int off = 1; off < 64; off <<= 1) {
    const int v = __shfl_up(winc, off, 64);
    if (t >= off) winc += v;
  }
  const int woff = winc - nw;
  const int wtot = __shfl(winc, 63, 64);  // total workers <= 576

  for (int wi = 0; wi < nw; ++wi) {  // independent stores, parallel across t
    wk[woff + wi] = (unsigned char)t;
    wbase[woff + wi] = seg + wi * WROWS;
    wcnt[woff + wi] = min(WROWS, c - wi * WROWS);
  }
  for (int w = wtot + t; w < GRIDW; w += 64) wk[w] = 255;
}

// scatter (R7 verbatim, validated): counting-sort x into xsort.
__global__ __launch_bounds__(256) void scatter_kernel(
    const float* __restrict__ x, const unsigned char* __restrict__ pred_g,
    int* __restrict__ cursor, float* __restrict__ xsort) {
  __shared__ int histS[KK];
  __shared__ int baseS[KK];
  __shared__ int slotS[256];

  const int tid = threadIdx.x;
  if (tid < KK) histS[tid] = 0;
  __syncthreads();

  const int row = blockIdx.x * 256 + tid;
  const int bi = pred_g[row];
  const int rank = atomicAdd(&histS[bi], 1);
  __syncthreads();
  if (tid < KK) {
    const int h = histS[tid];
    baseS[tid] = h ? atomicAdd(&cursor[tid], h) : 0;
  }
  __syncthreads();
  slotS[tid] = baseS[bi] + rank;
  __syncthreads();

  const float4* xin = (const float4*)x + (size_t)blockIdx.x * 2048;
  float4* xo = (float4*)xsort;
#pragma unroll
  for (int j = 0; j < 8; ++j) {
    const int f = tid + 256 * j;
    const int rl = f >> 3;
    const int pt = f & 7;
    xo[(size_t)slotS[rl] * 8 + pt] = xin[f];  // reads perfectly coalesced
  }
}

// syrk v3 (R7 verbatim, validated): worker = (cluster k, <=256 contiguous
// sorted rows); coalesced gather into transposed LDS tile; 2x2 register tile;
// lower-triangle flush.
__global__ __launch_bounds__(256) void syrk_kernel(
    const float* __restrict__ xsort, const unsigned char* __restrict__ wk,
    const int* __restrict__ wbase, const int* __restrict__ wcnt,
    float* __restrict__ m2low_g, float* __restrict__ sums_g) {
  __shared__ float xsT[DD][68];  // transposed tile, 8.7 KB

  const int b = blockIdx.x;
  const int k = wk[b];
  if (k == 255) return;
  const int tid = threadIdx.x;
  const int base = wbase[b];
  const int total = wcnt[b];

  const int ti = tid >> 4, tj = tid & 15;
  const int i0 = ti, i1 = ti + 16, j0 = tj, j1 = tj + 16;
  float c00 = 0.f, c10 = 0.f, c11 = 0.f, sd0 = 0.f, sd1 = 0.f;

  for (int off = 0; off < total; off += 64) {
    const int cnt = min(64, total - off);
    const int cnt4 = (cnt + 3) & ~3;
    __syncthreads();  // previous tile's readers done before overwrite
    const float* src = xsort + (size_t)(base + off) * DD;
    for (int e = tid; e < cnt * DD; e += 256)
      xsT[e & 31][e >> 5] = src[e];  // fully coalesced
    for (int e = cnt * DD + tid; e < cnt4 * DD; e += 256)
      xsT[e & 31][e >> 5] = 0.f;  // zero-pad rows to multiple of 4
    __syncthreads();
    for (int g = 0; g < (cnt4 >> 2); ++g) {
      const float4 A0 = *(const float4*)&xsT[i0][4 * g];
      const float4 A1 = *(const float4*)&xsT[i1][4 * g];
      const float4 B0 = *(const float4*)&xsT[j0][4 * g];
      const float4 B1 = *(const float4*)&xsT[j1][4 * g];
      c00 += A0.x * B0.x + A0.y * B0.y + A0.z * B0.z + A0.w * B0.w;
      c10 += A1.x * B0.x + A1.y * B0.y + A1.z * B0.z + A1.w * B0.w;
      c11 += A1.x * B1.x + A1.y * B1.y + A1.z * B1.z + A1.w * B1.w;
      if (tj == 0) {
        sd0 += A0.x + A0.y + A0.z + A0.w;
        sd1 += A1.x + A1.y + A1.z + A1.w;
      }
    }
  }

  float* m2k = m2low_g + k * 528;
  atomicAdd(&m2k[TRI(i1, j0)], c10);
  if (tj <= ti) {
    atomicAdd(&m2k[TRI(i0, j0)], c00);
    atomicAdd(&m2k[TRI(i1, j1)], c11);
  }
  if (tj == 0) {
    atomicAdd(&sums_g[k * DD + i0], sd0);
    atomicAdd(&sums_g[k * DD + i1], sd1);
  }
}

// finalize A (validated): one block per cluster.
__global__ __launch_bounds__(256) void finalizeA_kernel(
    const float* __restrict__ fill_g, const int* __restrict__ hist_g,
    const float* __restrict__ sums_g, const float* __restrict__ m2low_g,
    const float* __restrict__ ft, const float* __restrict__ mt,
    const float* __restrict__ ct, float* __restrict__ lossAcc) {
  __shared__ float meanS[DD];
  __shared__ float wred[4];
  const int t = threadIdx.x;
  const int k = blockIdx.x;

  const float inv = 1.0f / fmaxf((float)hist_g[k], 1.0f);
  if (t < DD) meanS[t] = sums_g[k * DD + t] * inv;
  __syncthreads();

  float acc = 0.f;
  if (t < DD) {
    const float d = meanS[t] - mt[k * DD + t];
    acc += d * d * (1.0f / (KK * DD));
  }
  if (t == 0) {
    const float f = fill_g[k] * (1.0f / (float)NR) - ft[k];
    acc += f * f * (1.0f / KK);
  }
  const float* m2k = m2low_g + k * 528;
  const float* ctk = ct + k * (DD * DD);
#pragma unroll
  for (int u = 0; u < 4; ++u) {
    const int e = t + 256 * u;
    const int i = e >> 5, j = e & 31;
    const int idx = (i >= j) ? TRI(i, j) : TRI(j, i);
    const float cov = m2k[idx] * inv - meanS[i] * meanS[j];
    const float d = cov - ctk[e];
    acc += d * d * (1.0f / (KK * DD * DD));
  }

  acc += __shfl_xor(acc, 32, 64);
  acc += __shfl_xor(acc, 16, 64);
  acc += __shfl_xor(acc, 8, 64);
  acc += __shfl_xor(acc, 4, 64);
  acc += __shfl_xor(acc, 2, 64);
  acc += __shfl_xor(acc, 1, 64);
  if ((t & 63) == 0) wred[t >> 6] = acc;
  __syncthreads();
  if (t == 0) atomicAdd(lossAcc, wred[0] + wred[1] + wred[2] + wred[3]);
}

__global__ void finalizeB_kernel(const float* __restrict__ lossAcc,
                                 float* __restrict__ out) {
  if (threadIdx.x == 0) out[0] = lossAcc[0];
}

extern "C" void kernel_launch(void* const* d_in, const int* in_sizes, int n_in,
                              void* d_out, int out_size, void* d_ws,
                              size_t ws_size, hipStream_t stream) {
  (void)in_sizes; (void)n_in; (void)out_size; (void)ws_size;
  const float* x = (const float*)d_in[0];
  const float* centers = (const float*)d_in[1];
  const float* ft = (const float*)d_in[2];
  const float* mt = (const float*)d_in[3];
  const float* ct = (const float*)d_in[4];
  float* out = (float*)d_out;

  float* ws = (float*)d_ws;
  float* fill_g = ws;                                   // 64
  float* lossAcc = ws + 64;                             // 1
  int* hist_g = (int*)(ws + 128);                       // 64
  int* segStart = (int*)(ws + 192);                     // 65
  int* cursor = (int*)(ws + 320);                       // 64
  unsigned char* wk = (unsigned char*)(ws + 384);       // GRIDW bytes
  int* wbase = (int*)(ws + 544);                        // GRIDW
  int* wcnt = (int*)(ws + 1184);                        // GRIDW
  float* m2low_g = ws + 1824;                           // 33792
  float* sums_g = ws + 35616;                           // 2048
  unsigned char* pred8 = (unsigned char*)(ws + 37664);  // N bytes
  float* xsort = ws + 70432;                            // N*D floats (16 MB)

  hipMemsetAsync(d_ws, 0, (size_t)37664 * sizeof(float), stream);

  phase1_kernel<<<NR / 256, 256, 0, stream>>>(x, centers, fill_g, hist_g,
                                              pred8);
  planner_kernel<<<1, 64, 0, stream>>>(hist_g, segStart, cursor, wk, wbase,
                                       wcnt);
  scatter_kernel<<<NR / 256, 256, 0, stream>>>(x, pred8, cursor, xsort);
  syrk_kernel<<<GRIDW, 256, 0, stream>>>(xsort, wk, wbase, wcnt, m2low_g,
                                         sums_g);
  finalizeA_kernel<<<KK, 256, 0, stream>>>(fill_g, hist_g, sums_g, m2low_g, ft,
                                           mt, ct, lossAcc);
  finalizeB_kernel<<<1, 64, 0, stream>>>(lossAcc, out);
}